// Round 11
// baseline (8329.814 us; speedup 1.0000x reference)
//
#include <hip/hip_runtime.h>
#include <stdint.h>

#define BATCH 256
#define SEQT  512
#define HID   1024
#define NCLS  128

using bf16x8 = __attribute__((ext_vector_type(8))) short;   // 8 bf16 (4 VGPRs)
using f32x4  = __attribute__((ext_vector_type(4))) float;
using i32x4  = __attribute__((ext_vector_type(4))) int;

__device__ __forceinline__ unsigned short f2bf(float x) {
    unsigned u = __float_as_uint(x);
    u = u + 0x7FFFu + ((u >> 16) & 1u);          // round-to-nearest-even
    return (unsigned short)(u >> 16);
}
__device__ __forceinline__ float bf2f(unsigned short s) {
    return __uint_as_float(((unsigned)s) << 16);
}
__device__ __forceinline__ float sigf(float x) { return 1.f / (1.f + __expf(-x)); }
__device__ __forceinline__ float tanhf_(float x) {
    x = fminf(12.f, fmaxf(-12.f, x));
    float e = __expf(2.f * x);
    return (e - 1.f) / (e + 1.f);
}

// agent-coherent 16B load: bypasses L1/L2 (sc1), reads the MALL coherence point.
// No waitcnt inside — caller manages counted vmcnt.
__device__ __forceinline__ void ld_a_sc1(bf16x8& d, const unsigned short* p) {
    asm volatile("global_load_dwordx4 %0, %1, off sc1" : "=v"(d) : "v"(p));
}

__device__ __forceinline__ unsigned ag_load(unsigned* p) {
    return __hip_atomic_load(p, __ATOMIC_RELAXED, __HIP_MEMORY_SCOPE_AGENT);
}
__device__ __forceinline__ void ag_store(unsigned* p, unsigned v) {
    __hip_atomic_store(p, v, __ATOMIC_RELAXED, __HIP_MEMORY_SCOPE_AGENT);
}
__device__ __forceinline__ unsigned ag_add(unsigned* p) {
    return __hip_atomic_fetch_add(p, 1u, __ATOMIC_RELAXED, __HIP_MEMORY_SCOPE_AGENT);
}

// x[256][512] -> xT[512][256] so per-step index loads are contiguous int4
__global__ void xtrans_kernel(const int* __restrict__ x, int* __restrict__ xT) {
    int b = blockIdx.x;
    for (int t = threadIdx.x; t < SEQT; t += 256) xT[t * BATCH + b] = x[b * SEQT + t];
}

// Persistent LSTM. Grid 512 x 256, 2 blocks/CU by capacity (LDS 12KB,
// VGPR <= 256). PLACEMENT-INDEPENDENT: global ticket; slot s -> panel s>>6
// (rows [32p,32p+32)), col group s&63 (16 hu x 4 gates).
//   B: 32 frags fully in registers, loaded once (persistent).
//   A: direct sc1 frag loads — ALL 16 issued up front (one MALL latency per
//      step), consumed with descending vmcnt(14..0). 64 VGPR in flight.
//   xw: idx prefetched during barrier wait; Wx gathers issued after K-loop
//       (L2-cached), consumed in finalize — keeps K-loop register pressure low.
//   h-stores: agent-scope dword write-through -> MALL; release = syncthreads.
//   barrier : monotonic distributed counters — 8 lines/panel, target 8*(t+1);
//             wave0 lanes 0..7 poll in parallel, ballot detection.
// Liveness: bounded waits; timeout -> abortf + 100.0 sentinels, never a hang.
__global__ void __launch_bounds__(256, 2) lstm_pers(
    const int* __restrict__ xT,
    const float* __restrict__ Wxg, const float* __restrict__ Whg, const float* __restrict__ b_g,
    const float* __restrict__ Wxi, const float* __restrict__ Whi, const float* __restrict__ b_i,
    const float* __restrict__ Wxf, const float* __restrict__ Whf, const float* __restrict__ b_f,
    const float* __restrict__ Wxo, const float* __restrict__ Who, const float* __restrict__ b_o,
    unsigned short* __restrict__ hbuf, unsigned int* __restrict__ cnt,
    unsigned int* __restrict__ misc)
{
    extern __shared__ char lds[];
    const int tid = threadIdx.x;
    const int w   = tid >> 6;       // wave 0..3: K-quarter w; waves 0,1 finalize frag 0,1
    const int l   = tid & 63;
    const int lHi = l >> 4;         // 0..3
    const int lLo = l & 15;

    volatile int* bailp = (volatile int*)(lds + 12288);
    volatile int* bcast = (volatile int*)(lds + 12292);
    unsigned* abortf  = misc + 0;
    unsigned* gticket = misc + 16;

    if (tid == 0) {
        *bailp = 0;
        bcast[0] = (int)ag_add(gticket);   // global slot 0..511, placement-independent
    }
    __syncthreads();
    const int slot  = bcast[0];
    const int panel = slot >> 6;           // batch-row panel 0..7
    const int r0    = panel * 32;
    const int hu0   = (slot & 63) * 16;    // my 16 hidden units (cols g|i|f|o x 16)

    // ---- one-time: B slice -> registers. Frag (kk,g): lane l holds
    // W[k = w*256 + kk*32 + lHi*8 + e][hu0 + lLo] for gate g, e=0..7.
    bf16x8 B0[8][4];
#pragma unroll
    for (int kk = 0; kk < 8; ++kk) {
#pragma unroll
        for (int g = 0; g < 4; ++g) {
            const float* Wsrc = (g == 0) ? Whg : (g == 1) ? Whi : (g == 2) ? Whf : Who;
            const size_t kb = (size_t)((w << 8) + kk * 32 + (lHi << 3));
#pragma unroll
            for (int e = 0; e < 8; ++e)
                B0[kk][g][e] = (short)f2bf(Wsrc[(kb + e) * HID + hu0 + lLo]);
        }
    }

    const int hu = hu0 + lLo;
    const float vbg = b_g[hu], vbi = b_i[hu], vbf = b_f[hu], vbo = b_o[hu];

    char* pb = lds;                         // 12KB exchange buffer
    float cst[4] = {0.f, 0.f, 0.f, 0.f};    // c-state (waves 0,1): 4 rows x 1 hu

    // my barrier line (one add per block) and poll lines (wave 0)
    unsigned* addline  = cnt + ((panel * 8 + (slot & 7)) << 4);
    unsigned* pollline = cnt + ((panel * 8 + (l & 7)) << 4);

    // idx prefetch state (for step t, loaded during step t-1's barrier wait)
    i32x4 idx;
    if (w < 2) idx = *(const i32x4*)(xT + 0 * BATCH + r0 + w * 16 + (lHi << 2));

    for (int t = 0; t < SEQT; ++t) {
        const unsigned short* cur = hbuf + (size_t)(t & 1) * BATCH * HID;
        unsigned short*       nxt = hbuf + (size_t)((t + 1) & 1) * BATCH * HID;

        const unsigned short* a0 = cur + (size_t)(r0 + lLo) * HID + ((w << 8) + (lHi << 3));
        const unsigned short* a1 = a0 + 16 * HID;

        f32x4 acc[2][4];                    // [m-frag][gate]
#pragma unroll
        for (int m = 0; m < 2; ++m)
#pragma unroll
            for (int g = 0; g < 4; ++g) acc[m][g] = (f32x4){0.f, 0.f, 0.f, 0.f};

        // ---- K-loop: issue ALL 16 sc1 loads up front (one MALL latency),
        // then consume with descending counted vmcnt.
        bf16x8 pf[8][2];
#pragma unroll
        for (int kk = 0; kk < 8; ++kk) {
            ld_a_sc1(pf[kk][0], a0 + kk * 32);
            ld_a_sc1(pf[kk][1], a1 + kk * 32);
        }
#pragma unroll
        for (int kk = 0; kk < 8; ++kk) {
            switch (kk) {
                case 0: asm volatile("s_waitcnt vmcnt(14)" ::: "memory"); break;
                case 1: asm volatile("s_waitcnt vmcnt(12)" ::: "memory"); break;
                case 2: asm volatile("s_waitcnt vmcnt(10)" ::: "memory"); break;
                case 3: asm volatile("s_waitcnt vmcnt(8)"  ::: "memory"); break;
                case 4: asm volatile("s_waitcnt vmcnt(6)"  ::: "memory"); break;
                case 5: asm volatile("s_waitcnt vmcnt(4)"  ::: "memory"); break;
                case 6: asm volatile("s_waitcnt vmcnt(2)"  ::: "memory"); break;
                default: asm volatile("s_waitcnt vmcnt(0)" ::: "memory"); break;
            }
            __builtin_amdgcn_sched_barrier(0);
#pragma unroll
            for (int g = 0; g < 4; ++g) {
                acc[0][g] = __builtin_amdgcn_mfma_f32_16x16x32_bf16(pf[kk][0], B0[kk][g], acc[0][g], 0, 0, 0);
                acc[1][g] = __builtin_amdgcn_mfma_f32_16x16x32_bf16(pf[kk][1], B0[kk][g], acc[1][g], 0, 0, 0);
            }
        }

        // ---- xw gathers (waves 0,1 only): L2-cached Wx rows, hidden under exchange
        float xw0[4], xw1[4], xw2[4], xw3[4];
        if (w < 2) {
#pragma unroll
            for (int r = 0; r < 4; ++r) {
                xw0[r] = Wxg[(size_t)idx[r] * HID + hu];
                xw1[r] = Wxi[(size_t)idx[r] * HID + hu];
                xw2[r] = Wxf[(size_t)idx[r] * HID + hu];
                xw3[r] = Wxo[(size_t)idx[r] * HID + hu];
            }
        }

        // ---- cross-wave K-reduction: frag m's partials -> finalizer wave m
        const int bailed = *bailp;
#pragma unroll
        for (int m = 0; m < 2; ++m) {
            if (w != m) {
                const int src = (w < m) ? w : (w - 1);   // 0..2 among non-owners
#pragma unroll
                for (int g = 0; g < 4; ++g) {
                    union { unsigned short us[4]; unsigned long long v64; } pk;
#pragma unroll
                    for (int r = 0; r < 4; ++r) pk.us[r] = f2bf(acc[m][g][r]);
                    *(unsigned long long*)(pb + ((m * 3 + src) * 4 + g) * 512 + l * 8) = pk.v64;
                }
            }
        }
        __syncthreads();

        if (w < 2) {
            const int m = w;
            float pre[4][4];
#pragma unroll
            for (int g = 0; g < 4; ++g) {
#pragma unroll
                for (int r = 0; r < 4; ++r) pre[g][r] = acc[m][g][r];
#pragma unroll
                for (int s = 0; s < 3; ++s) {
                    union { unsigned short us[4]; unsigned long long v64; } pk;
                    pk.v64 = *(const unsigned long long*)(pb + ((m * 3 + s) * 4 + g) * 512 + l * 8);
#pragma unroll
                    for (int r = 0; r < 4; ++r) pre[g][r] += bf2f(pk.us[r]);
                }
            }
#pragma unroll
            for (int r = 0; r < 4; ++r) {
                float gg = tanhf_(pre[0][r] + xw0[r] + vbg);
                float ii = sigf  (pre[1][r] + xw1[r] + vbi);
                float ff = sigf  (pre[2][r] + xw2[r] + vbf);
                float oo = sigf  (pre[3][r] + xw3[r] + vbo);
                cst[r] = gg * ii + cst[r] * ff;
                float hv = tanhf_(cst[r]) * oo;
                unsigned short hs = bailed ? (unsigned short)0x42C8 : f2bf(hv); // 100.0 sentinel
                unsigned pk32 = (unsigned)hs;
                unsigned oth  = (unsigned)__shfl_xor((int)pk32, 1, 64) & 0xFFFFu;
                if ((lLo & 1) == 0) {
                    unsigned v32 = pk32 | (oth << 16);
                    unsigned* p32 = (unsigned*)&nxt[(size_t)(r0 + m * 16 + (lHi << 2) + r) * HID + hu];
                    __hip_atomic_store(p32, v32, __ATOMIC_RELAXED, __HIP_MEMORY_SCOPE_AGENT);
                }
            }
        }
        __syncthreads();   // drains vmcnt in EVERY wave: h visible at MALL

        // ---- panel barrier: monotonic distributed counters (8 lines/panel)
        if (tid == 0) ag_add(addline);

        // prefetch next step's indices during the wait (4 VGPR only)
        if (w < 2) {
            const int tn = (t + 1 < SEQT) ? t + 1 : t;
            idx = *(const i32x4*)(xT + tn * BATCH + r0 + w * 16 + (lHi << 2));
        }

        if (w == 0 && !(*bailp)) {
            const unsigned target = 8u * (unsigned)(t + 1);
            unsigned guard = 0;
            bool ok = false;
            for (;;) {
                bool done = ag_load(pollline) >= target;        // lanes 0..7 cover 8 lines
                if (__ballot(done) == ~0ull) { ok = true; break; }
                unsigned ab = ((guard & 63u) == 0u) ? ag_load(abortf) : 0u;  // uniform
                if (ab) break;
                __builtin_amdgcn_s_sleep(1);
                if (++guard > (1u << 17)) {
                    if (l == 0) ag_store(abortf, 1u);
                    break;
                }
            }
            if (!ok && l == 0) *bailp = 1;                       // sticky, sentinel next step
        }
        __syncthreads();
        // no fence: next step's sc1 loads read the MALL directly
    }
}

// out[256][128] = h_512 @ W_hp + b_p  (h_512 in hbuf[0]; dispatch-boundary
// acquire makes the MALL-resident h visible to this kernel)
__global__ void __launch_bounds__(256, 1) proj_kernel(
    const unsigned short* __restrict__ h, const float* __restrict__ Whp,
    const float* __restrict__ bp, float* __restrict__ out)
{
    __shared__ float red[4][256];
    const int tid  = threadIdx.x;
    const int n    = tid & 127;
    const int half = tid >> 7;
    const int b0   = blockIdx.x * 4;
    float s0 = 0.f, s1 = 0.f, s2 = 0.f, s3 = 0.f;
    for (int k = half * 512; k < half * 512 + 512; ++k) {
        float wv = Whp[(size_t)k * NCLS + n];
        s0 += bf2f(h[(size_t)(b0 + 0) * HID + k]) * wv;
        s1 += bf2f(h[(size_t)(b0 + 1) * HID + k]) * wv;
        s2 += bf2f(h[(size_t)(b0 + 2) * HID + k]) * wv;
        s3 += bf2f(h[(size_t)(b0 + 3) * HID + k]) * wv;
    }
    red[0][tid] = s0; red[1][tid] = s1; red[2][tid] = s2; red[3][tid] = s3;
    __syncthreads();
    if (tid < 128) {
#pragma unroll
        for (int j = 0; j < 4; ++j)
            out[(size_t)(b0 + j) * NCLS + tid] = red[j][tid] + red[j][tid + 128] + bp[tid];
    }
}

extern "C" void kernel_launch(void* const* d_in, const int* in_sizes, int n_in,
                              void* d_out, int out_size, void* d_ws, size_t ws_size,
                              hipStream_t stream) {
    const int*   x   = (const int*)  d_in[0];
    const float* Wxg = (const float*)d_in[1];
    const float* Whg = (const float*)d_in[2];
    const float* b_g = (const float*)d_in[3];
    const float* Wxi = (const float*)d_in[4];
    const float* Whi = (const float*)d_in[5];
    const float* b_i = (const float*)d_in[6];
    const float* Wxf = (const float*)d_in[7];
    const float* Whf = (const float*)d_in[8];
    const float* b_f = (const float*)d_in[9];
    const float* Wxo = (const float*)d_in[10];
    const float* Who = (const float*)d_in[11];
    const float* b_o = (const float*)d_in[12];
    const float* Whp = (const float*)d_in[13];
    const float* b_p = (const float*)d_in[14];
    float* out = (float*)d_out;

    char* ws = (char*)d_ws;
    unsigned short* hbuf = (unsigned short*)ws;                           // 2*256*1024 bf16 = 1 MB
    int*            xT   = (int*)(ws + (1 << 20));                        // 512 KB
    unsigned int*   cnt  = (unsigned int*)(ws + (1 << 20) + (512*1024));  // 64 lines x 64B = 4 KB
    unsigned int*   misc = cnt + 64 * 16;                                 // abortf, gticket (64B apart)

    // re-zero per call (capture-safe; re-runs on every replay):
    //   h_0 = 0; barrier lines + abortf + gticket = 0.
    hipMemsetAsync(hbuf, 0, (size_t)BATCH * HID * sizeof(unsigned short), stream);
    hipMemsetAsync(cnt, 0, (size_t)(64 * 16 + 32) * sizeof(unsigned int), stream);

    xtrans_kernel<<<256, 256, 0, stream>>>(x, xT);

    const int ldsBytes = 12288 + 64;        // exchange + flags
    (void)hipFuncSetAttribute((const void*)lstm_pers,
                              hipFuncAttributeMaxDynamicSharedMemorySize, ldsBytes);
    lstm_pers<<<512, 256, ldsBytes, stream>>>(xT, Wxg, Whg, b_g, Wxi, Whi, b_i,
                                              Wxf, Whf, b_f, Wxo, Who, b_o, hbuf, cnt, misc);

    proj_kernel<<<64, 256, 0, stream>>>(hbuf, Whp, b_p, out);
}

// Round 12
// 3437.782 us; speedup vs baseline: 2.4230x; 2.4230x over previous
//
#include <hip/hip_runtime.h>
#include <stdint.h>

#define BATCH 256
#define SEQT  512
#define HID   1024
#define NCLS  128

using bf16x8 = __attribute__((ext_vector_type(8))) short;   // 8 bf16 (4 VGPRs)
using f32x4  = __attribute__((ext_vector_type(4))) float;
using i32x2  = __attribute__((ext_vector_type(2))) int;

__device__ __forceinline__ unsigned short f2bf(float x) {
    unsigned u = __float_as_uint(x);
    u = u + 0x7FFFu + ((u >> 16) & 1u);          // round-to-nearest-even
    return (unsigned short)(u >> 16);
}
__device__ __forceinline__ float bf2f(unsigned short s) {
    return __uint_as_float(((unsigned)s) << 16);
}
__device__ __forceinline__ float sigf(float x) { return 1.f / (1.f + __expf(-x)); }
__device__ __forceinline__ float tanhf_(float x) {
    x = fminf(12.f, fmaxf(-12.f, x));
    float e = __expf(2.f * x);
    return (e - 1.f) / (e + 1.f);
}

// agent-coherent 16B load: bypasses L1/L2 (sc1), reads the MALL coherence point.
// No waitcnt inside — caller manages counted vmcnt.
__device__ __forceinline__ void ld_a_sc1(bf16x8& d, const unsigned short* p) {
    asm volatile("global_load_dwordx4 %0, %1, off sc1" : "=v"(d) : "v"(p));
}

__device__ __forceinline__ unsigned ag_load(unsigned* p) {
    return __hip_atomic_load(p, __ATOMIC_RELAXED, __HIP_MEMORY_SCOPE_AGENT);
}
__device__ __forceinline__ void ag_store(unsigned* p, unsigned v) {
    __hip_atomic_store(p, v, __ATOMIC_RELAXED, __HIP_MEMORY_SCOPE_AGENT);
}
__device__ __forceinline__ unsigned ag_add(unsigned* p) {
    return __hip_atomic_fetch_add(p, 1u, __ATOMIC_RELAXED, __HIP_MEMORY_SCOPE_AGENT);
}

// x[256][512] -> xT[512][256] so per-step index loads are contiguous
__global__ void xtrans_kernel(const int* __restrict__ x, int* __restrict__ xT) {
    int b = blockIdx.x;
    for (int t = threadIdx.x; t < SEQT; t += 256) xT[t * BATCH + b] = x[b * SEQT + t];
}

// Persistent LSTM. Grid 512 x 256, 2 blocks/CU by capacity (LDS 12KB,
// ~128 VGPR + 128 AGPR unified). PLACEMENT-INDEPENDENT global ticket;
// slot s -> panel s>>6 (rows [32p,32p+32)), col group s&63 (16 hu x 4 gates).
//   B: 32 frags in registers/AGPRs, loaded once (persistent).
//   A: direct sc1 frag loads, R10-proven depth-3-ahead pipeline (6 outstanding,
//      vmcnt 6/4/2/0). No staging, no spills.
//   finalize: 4-WAY SPLIT — wave w owns frag w>>1, row-half w&1 (2 rows/lane).
//   h-stores: agent-scope dword write-through -> MALL; release = syncthreads.
//   barrier : monotonic distributed counters — 8 lines/panel, target 8*(t+1);
//             wave0 lanes 0..7 poll in parallel, ballot detect, first check
//             without sleep. xw gathers hidden in the wait window.
// Liveness: bounded waits; timeout -> abortf + 100.0 sentinels, never a hang.
__global__ void __launch_bounds__(256, 2) lstm_pers(
    const int* __restrict__ xT,
    const float* __restrict__ Wxg, const float* __restrict__ Whg, const float* __restrict__ b_g,
    const float* __restrict__ Wxi, const float* __restrict__ Whi, const float* __restrict__ b_i,
    const float* __restrict__ Wxf, const float* __restrict__ Whf, const float* __restrict__ b_f,
    const float* __restrict__ Wxo, const float* __restrict__ Who, const float* __restrict__ b_o,
    unsigned short* __restrict__ hbuf, unsigned int* __restrict__ cnt,
    unsigned int* __restrict__ misc)
{
    extern __shared__ char lds[];
    const int tid = threadIdx.x;
    const int w   = tid >> 6;       // wave 0..3: K-quarter w; finalizes (w>>1, w&1)
    const int l   = tid & 63;
    const int lHi = l >> 4;         // 0..3
    const int lLo = l & 15;

    volatile int* bailp = (volatile int*)(lds + 12288);
    volatile int* bcast = (volatile int*)(lds + 12292);
    unsigned* abortf  = misc + 0;
    unsigned* gticket = misc + 16;

    if (tid == 0) {
        *bailp = 0;
        bcast[0] = (int)ag_add(gticket);   // global slot 0..511, placement-independent
    }
    __syncthreads();
    const int slot  = bcast[0];
    const int panel = slot >> 6;           // batch-row panel 0..7
    const int r0    = panel * 32;
    const int hu0   = (slot & 63) * 16;    // my 16 hidden units (cols g|i|f|o x 16)

    // ---- one-time: B slice -> registers. Frag (kk,g): lane l holds
    // W[k = w*256 + kk*32 + lHi*8 + e][hu0 + lLo] for gate g, e=0..7.
    bf16x8 B0[8][4];
#pragma unroll
    for (int kk = 0; kk < 8; ++kk) {
#pragma unroll
        for (int g = 0; g < 4; ++g) {
            const float* Wsrc = (g == 0) ? Whg : (g == 1) ? Whi : (g == 2) ? Whf : Who;
            const size_t kb = (size_t)((w << 8) + kk * 32 + (lHi << 3));
#pragma unroll
            for (int e = 0; e < 8; ++e)
                B0[kk][g][e] = (short)f2bf(Wsrc[(kb + e) * HID + hu0 + lLo]);
        }
    }

    const int hu = hu0 + lLo;
    const float vbg = b_g[hu], vbi = b_i[hu], vbf = b_f[hu], vbo = b_o[hu];

    char* pb = lds;                         // 12KB exchange buffer
    const int fm  = w >> 1;                 // my finalize frag
    const int fhf = w & 1;                  // my finalize row-half
    float cst[2] = {0.f, 0.f};              // c-state: 2 rows x 1 hu per lane
    // my finalize rows (global): r0 + fm*16 + lHi*4 + 2*fhf + rr
    const int frow = r0 + fm * 16 + (lHi << 2) + 2 * fhf;

    // my barrier line (one add per block) and poll lines (wave 0)
    unsigned* addline  = cnt + ((panel * 8 + (slot & 7)) << 4);
    unsigned* pollline = cnt + ((panel * 8 + (l & 7)) << 4);

    // xw state for step t (gathered during step t-1's barrier window)
    float xw[4][2];
    {
        i32x2 idx = *(const i32x2*)(xT + 0 * BATCH + frow);
#pragma unroll
        for (int rr = 0; rr < 2; ++rr) {
            xw[0][rr] = Wxg[(size_t)idx[rr] * HID + hu];
            xw[1][rr] = Wxi[(size_t)idx[rr] * HID + hu];
            xw[2][rr] = Wxf[(size_t)idx[rr] * HID + hu];
            xw[3][rr] = Wxo[(size_t)idx[rr] * HID + hu];
        }
    }

    for (int t = 0; t < SEQT; ++t) {
        const unsigned short* cur = hbuf + (size_t)(t & 1) * BATCH * HID;
        unsigned short*       nxt = hbuf + (size_t)((t + 1) & 1) * BATCH * HID;

        const unsigned short* a0 = cur + (size_t)(r0 + lLo) * HID + ((w << 8) + (lHi << 3));
        const unsigned short* a1 = a0 + 16 * HID;

        f32x4 acc[2][4];                    // [m-frag][gate]
#pragma unroll
        for (int m = 0; m < 2; ++m)
#pragma unroll
            for (int g = 0; g < 4; ++g) acc[m][g] = (f32x4){0.f, 0.f, 0.f, 0.f};

        // ---- K-loop: direct sc1 frag loads, R10 depth-3-ahead, counted vmcnt
        bf16x8 pf[4][2];
        ld_a_sc1(pf[0][0], a0 + 0 * 32);  ld_a_sc1(pf[0][1], a1 + 0 * 32);
        ld_a_sc1(pf[1][0], a0 + 1 * 32);  ld_a_sc1(pf[1][1], a1 + 1 * 32);
        ld_a_sc1(pf[2][0], a0 + 2 * 32);  ld_a_sc1(pf[2][1], a1 + 2 * 32);
#pragma unroll
        for (int kk = 0; kk < 8; ++kk) {
            if (kk < 5) {
                ld_a_sc1(pf[(kk + 3) & 3][0], a0 + (kk + 3) * 32);
                ld_a_sc1(pf[(kk + 3) & 3][1], a1 + (kk + 3) * 32);
            }
            if      (kk < 5)  asm volatile("s_waitcnt vmcnt(6)" ::: "memory");
            else if (kk == 5) asm volatile("s_waitcnt vmcnt(4)" ::: "memory");
            else if (kk == 6) asm volatile("s_waitcnt vmcnt(2)" ::: "memory");
            else              asm volatile("s_waitcnt vmcnt(0)" ::: "memory");
            __builtin_amdgcn_sched_barrier(0);
#pragma unroll
            for (int g = 0; g < 4; ++g) {
                acc[0][g] = __builtin_amdgcn_mfma_f32_16x16x32_bf16(pf[kk & 3][0], B0[kk][g], acc[0][g], 0, 0, 0);
                acc[1][g] = __builtin_amdgcn_mfma_f32_16x16x32_bf16(pf[kk & 3][1], B0[kk][g], acc[1][g], 0, 0, 0);
            }
        }

        // ---- exchange: for finalizer f=(f>>1, f&1) != w send its 2-row slice
        const int bailed = *bailp;
#pragma unroll
        for (int f = 0; f < 4; ++f) {
            if (f != w) {
                const int m_  = f >> 1;
                const int hf_ = f & 1;
                const int src = (w < f) ? w : (w - 1);   // 0..2 among non-f waves
#pragma unroll
                for (int g = 0; g < 4; ++g) {
                    unsigned pk = (unsigned)f2bf(acc[m_][g][2 * hf_ + 0]) |
                                  ((unsigned)f2bf(acc[m_][g][2 * hf_ + 1]) << 16);
                    *(unsigned*)(pb + ((f * 3 + src) * 4 + g) * 256 + l * 4) = pk;
                }
            }
        }
        __syncthreads();

        // ---- finalize (ALL 4 waves, 2 rows each): reduce + gates + h-store
#pragma unroll
        for (int f = 0; f < 4; ++f) {
            if (w == f) {                   // static acc indices inside (rule #20)
                const int m_  = f >> 1;
                const int hf_ = f & 1;
                float pre[4][2];
#pragma unroll
                for (int g = 0; g < 4; ++g) {
                    pre[g][0] = acc[m_][g][2 * hf_ + 0];
                    pre[g][1] = acc[m_][g][2 * hf_ + 1];
#pragma unroll
                    for (int s = 0; s < 3; ++s) {
                        unsigned pk = *(const unsigned*)(pb + ((f * 3 + s) * 4 + g) * 256 + l * 4);
                        pre[g][0] += bf2f((unsigned short)(pk & 0xFFFFu));
                        pre[g][1] += bf2f((unsigned short)(pk >> 16));
                    }
                }
#pragma unroll
                for (int rr = 0; rr < 2; ++rr) {
                    float gg = tanhf_(pre[0][rr] + xw[0][rr] + vbg);
                    float ii = sigf  (pre[1][rr] + xw[1][rr] + vbi);
                    float ff = sigf  (pre[2][rr] + xw[2][rr] + vbf);
                    float oo = sigf  (pre[3][rr] + xw[3][rr] + vbo);
                    cst[rr] = gg * ii + cst[rr] * ff;
                    float hv = tanhf_(cst[rr]) * oo;
                    unsigned short hs = bailed ? (unsigned short)0x42C8 : f2bf(hv); // 100.0 sentinel
                    unsigned pk32 = (unsigned)hs;
                    unsigned oth  = (unsigned)__shfl_xor((int)pk32, 1, 64) & 0xFFFFu;
                    if ((lLo & 1) == 0) {
                        unsigned v32 = pk32 | (oth << 16);
                        unsigned* p32 = (unsigned*)&nxt[(size_t)(frow + rr) * HID + hu];
                        __hip_atomic_store(p32, v32, __ATOMIC_RELAXED, __HIP_MEMORY_SCOPE_AGENT);
                    }
                }
            }
        }
        __syncthreads();   // drains vmcnt in EVERY wave: h visible at MALL

        // ---- panel barrier: monotonic distributed counters (8 lines/panel)
        if (tid == 0) ag_add(addline);

        // xw gathers for step t+1 during the wait (hidden, all waves)
        {
            const int tn = (t + 1 < SEQT) ? t + 1 : t;
            i32x2 idx = *(const i32x2*)(xT + tn * BATCH + frow);
#pragma unroll
            for (int rr = 0; rr < 2; ++rr) {
                xw[0][rr] = Wxg[(size_t)idx[rr] * HID + hu];
                xw[1][rr] = Wxi[(size_t)idx[rr] * HID + hu];
                xw[2][rr] = Wxf[(size_t)idx[rr] * HID + hu];
                xw[3][rr] = Wxo[(size_t)idx[rr] * HID + hu];
            }
        }

        if (w == 0 && !(*bailp)) {
            const unsigned target = 8u * (unsigned)(t + 1);
            unsigned guard = 0;
            bool ok = false;
            for (;;) {
                bool done = ag_load(pollline) >= target;        // lanes 0..7 cover 8 lines
                if (__ballot(done) == ~0ull) { ok = true; break; }   // first check: no sleep
                unsigned ab = ((guard & 63u) == 0u) ? ag_load(abortf) : 0u;  // uniform
                if (ab) break;
                __builtin_amdgcn_s_sleep(1);
                if (++guard > (1u << 17)) {
                    if (l == 0) ag_store(abortf, 1u);
                    break;
                }
            }
            if (!ok && l == 0) *bailp = 1;                       // sticky, sentinel next step
        }
        __syncthreads();
        // no fence: next step's sc1 loads read the MALL directly
    }
}

// out[256][128] = h_512 @ W_hp + b_p  (h_512 in hbuf[0]; dispatch-boundary
// acquire makes the MALL-resident h visible to this kernel)
__global__ void __launch_bounds__(256, 1) proj_kernel(
    const unsigned short* __restrict__ h, const float* __restrict__ Whp,
    const float* __restrict__ bp, float* __restrict__ out)
{
    __shared__ float red[4][256];
    const int tid  = threadIdx.x;
    const int n    = tid & 127;
    const int half = tid >> 7;
    const int b0   = blockIdx.x * 4;
    float s0 = 0.f, s1 = 0.f, s2 = 0.f, s3 = 0.f;
    for (int k = half * 512; k < half * 512 + 512; ++k) {
        float wv = Whp[(size_t)k * NCLS + n];
        s0 += bf2f(h[(size_t)(b0 + 0) * HID + k]) * wv;
        s1 += bf2f(h[(size_t)(b0 + 1) * HID + k]) * wv;
        s2 += bf2f(h[(size_t)(b0 + 2) * HID + k]) * wv;
        s3 += bf2f(h[(size_t)(b0 + 3) * HID + k]) * wv;
    }
    red[0][tid] = s0; red[1][tid] = s1; red[2][tid] = s2; red[3][tid] = s3;
    __syncthreads();
    if (tid < 128) {
#pragma unroll
        for (int j = 0; j < 4; ++j)
            out[(size_t)(b0 + j) * NCLS + tid] = red[j][tid] + red[j][tid + 128] + bp[tid];
    }
}

extern "C" void kernel_launch(void* const* d_in, const int* in_sizes, int n_in,
                              void* d_out, int out_size, void* d_ws, size_t ws_size,
                              hipStream_t stream) {
    const int*   x   = (const int*)  d_in[0];
    const float* Wxg = (const float*)d_in[1];
    const float* Whg = (const float*)d_in[2];
    const float* b_g = (const float*)d_in[3];
    const float* Wxi = (const float*)d_in[4];
    const float* Whi = (const float*)d_in[5];
    const float* b_i = (const float*)d_in[6];
    const float* Wxf = (const float*)d_in[7];
    const float* Whf = (const float*)d_in[8];
    const float* b_f = (const float*)d_in[9];
    const float* Wxo = (const float*)d_in[10];
    const float* Who = (const float*)d_in[11];
    const float* b_o = (const float*)d_in[12];
    const float* Whp = (const float*)d_in[13];
    const float* b_p = (const float*)d_in[14];
    float* out = (float*)d_out;

    char* ws = (char*)d_ws;
    unsigned short* hbuf = (unsigned short*)ws;                           // 2*256*1024 bf16 = 1 MB
    int*            xT   = (int*)(ws + (1 << 20));                        // 512 KB
    unsigned int*   cnt  = (unsigned int*)(ws + (1 << 20) + (512*1024));  // 64 lines x 64B = 4 KB
    unsigned int*   misc = cnt + 64 * 16;                                 // abortf, gticket (64B apart)

    // re-zero per call (capture-safe; re-runs on every replay):
    //   h_0 = 0; barrier lines + abortf + gticket = 0.
    hipMemsetAsync(hbuf, 0, (size_t)BATCH * HID * sizeof(unsigned short), stream);
    hipMemsetAsync(cnt, 0, (size_t)(64 * 16 + 32) * sizeof(unsigned int), stream);

    xtrans_kernel<<<256, 256, 0, stream>>>(x, xT);

    const int ldsBytes = 12288 + 64;        // exchange + flags
    (void)hipFuncSetAttribute((const void*)lstm_pers,
                              hipFuncAttributeMaxDynamicSharedMemorySize, ldsBytes);
    lstm_pers<<<512, 256, ldsBytes, stream>>>(xT, Wxg, Whg, b_g, Wxi, Whi, b_i,
                                              Wxf, Whf, b_f, Wxo, Who, b_o, hbuf, cnt, misc);

    proj_kernel<<<64, 256, 0, stream>>>(hbuf, Whp, b_p, out);
}